// Round 5
// baseline (3399.858 us; speedup 1.0000x reference)
//
#include <hip/hip_runtime.h>
#include <hip/hip_bf16.h>
#include <cstdint>
#include <cstddef>

#define TTOK 2048
#define DDIM 2048
#define FDIM 7168
#define NEXP 8

typedef __attribute__((ext_vector_type(8))) short bf16x8;
typedef __attribute__((ext_vector_type(4))) float f32x4;

// native RNE float->bf16 (compiler fuses pairs into v_cvt_pk_bf16_f32)
__device__ __forceinline__ unsigned short f2bf(float f) {
  __hip_bfloat16 h = __float2bfloat16(f);
  unsigned short s;
  __builtin_memcpy(&s, &h, 2);
  return s;
}

__device__ __forceinline__ bf16x8 pack8(float4 a, float4 b) {
  bf16x8 r;
  r[0] = (short)f2bf(a.x); r[1] = (short)f2bf(a.y);
  r[2] = (short)f2bf(a.z); r[3] = (short)f2bf(a.w);
  r[4] = (short)f2bf(b.x); r[5] = (short)f2bf(b.y);
  r[6] = (short)f2bf(b.z); r[7] = (short)f2bf(b.w);
  return r;
}

__device__ __forceinline__ void gload_lds16(const void* g, void* l) {
  __builtin_amdgcn_global_load_lds((const __attribute__((address_space(1))) void*)g,
                                   (__attribute__((address_space(3))) void*)l,
                                   16, 0, 0);
}

// ---------------- x -> bf16 ----------------
__global__ void cvt_x_kernel(const float* __restrict__ x, unsigned short* __restrict__ xb, int n4) {
  int i = blockIdx.x * blockDim.x + threadIdx.x;
  if (i >= n4) return;
  float4 v = ((const float4*)x)[i];
  ushort4 o;
  o.x = f2bf(v.x); o.y = f2bf(v.y); o.z = f2bf(v.z); o.w = f2bf(v.w);
  ((ushort4*)xb)[i] = o;
}

// ---------------- gate: fp32 logits, top-2, routing ----------------
__global__ void gate_kernel(const float* __restrict__ x, const float* __restrict__ gw,
                            int* __restrict__ counts, int* __restrict__ lists,
                            float* __restrict__ wrow) {
  const int wv = threadIdx.x >> 6, ln = threadIdx.x & 63;
  const int t = blockIdx.x * 4 + wv;
  float acc[8];
  #pragma unroll
  for (int e = 0; e < 8; ++e) acc[e] = 0.f;
  const float* xp = x + (size_t)t * DDIM;
  for (int d = ln; d < DDIM; d += 64) {
    float xv = xp[d];
    #pragma unroll
    for (int e = 0; e < 8; ++e) acc[e] += xv * gw[e * DDIM + d];
  }
  #pragma unroll
  for (int e = 0; e < 8; ++e) {
    float v = acc[e];
    #pragma unroll
    for (int off = 32; off > 0; off >>= 1) v += __shfl_down(v, off);
    acc[e] = v;
  }
  if (ln == 0) {
    int i0 = 0;
    #pragma unroll
    for (int e = 1; e < 8; ++e) if (acc[e] > acc[i0]) i0 = e;
    int i1 = (i0 == 0) ? 1 : 0;
    #pragma unroll
    for (int e = 0; e < 8; ++e) if (e != i0 && acc[e] > acc[i1]) i1 = e;
    float p1 = expf(acc[i1] - acc[i0]);
    float w0 = 1.f / (1.f + p1);
    float w1v = p1 / (1.f + p1);
    int pos0 = atomicAdd(&counts[i0], 1);
    lists[i0 * TTOK + pos0] = t; wrow[i0 * TTOK + pos0] = w0;
    int pos1 = atomicAdd(&counts[i1], 1);
    lists[i1 * TTOK + pos1] = t; wrow[i1 * TTOK + pos1] = w1v;
  }
}

__global__ void prefix_kernel(const int* __restrict__ counts, int* __restrict__ hoff) {
  if (threadIdx.x == 0) {
    int s = 0;
    for (int e = 0; e < NEXP; ++e) { hoff[e] = s; s += counts[e]; }
  }
}

// LDS tile: logical [128 rows][8 chunks of 8 bf16]; physical chunk = logical ^ (row&7).

// ---------------- GEMM1: H = silu(Xe@w1^T)*(Xe@w3^T)*wt ----------------
__launch_bounds__(256, 3)
__global__ void gemm1_kernel(const unsigned short* __restrict__ xb,
                             const float* __restrict__ w1,
                             const float* __restrict__ w3,
                             const int* __restrict__ counts,
                             const int* __restrict__ hoff,
                             const int* __restrict__ lists,
                             const float* __restrict__ wrow,
                             unsigned short* __restrict__ H) {
  const int ft = blockIdx.x, mt = blockIdx.y, e = blockIdx.z;
  const int cnt = counts[e];
  if (mt * 128 >= cnt) return;

  __shared__ __align__(16) unsigned short smA[128 * 64];
  __shared__ __align__(16) unsigned short smB1[128 * 64];
  __shared__ __align__(16) unsigned short smB3[128 * 64];
  __shared__ float smW[128];

  const int tid = threadIdx.x;
  const int wv = tid >> 6, ln = tid & 63;
  const int wr = wv >> 1, wc = wv & 1;

  if (tid < 128) {
    int pos = mt * 128 + tid;
    smW[tid] = (pos < cnt) ? wrow[e * TTOK + pos] : 0.f;
  }

  // A staging: global source pre-swizzled; linear glds dest yields swizzled LDS
  const int* lst = lists + e * TTOK;
  const int colA = (((ln & 7) ^ (ln >> 3)) * 8);
  const unsigned short* xap[4];
  #pragma unroll
  for (int q = 0; q < 4; ++q) {
    int pos = mt * 128 + q * 32 + wv * 8 + (ln >> 3);
    int tok = (pos < cnt) ? lst[pos] : 0;
    xap[q] = xb + (size_t)tok * DDIM + colA;
  }

  // B staging coords
  const int rowB = tid >> 1;
  const int halfB = tid & 1;
  const size_t eoff = (size_t)e * FDIM * DDIM;
  const float* w1p = w1 + eoff + (size_t)(ft * 128 + rowB) * DDIM + halfB * 32;
  const float* w3p = w3 + eoff + (size_t)(ft * 128 + rowB) * DDIM + halfB * 32;
  int physB[4];
  #pragma unroll
  for (int q = 0; q < 4; ++q) physB[q] = ((halfB * 4 + q) ^ (rowB & 7)) * 8;

  float4 bv1[8], bv3[8];

  f32x4 accG[4][4], accU[4][4];
  #pragma unroll
  for (int i = 0; i < 4; ++i)
    #pragma unroll
    for (int j = 0; j < 4; ++j) {
      accG[i][j] = (f32x4){0.f, 0.f, 0.f, 0.f};
      accU[i][j] = (f32x4){0.f, 0.f, 0.f, 0.f};
    }

  #define STAGE_A(KT) do { \
    _Pragma("unroll") \
    for (int q = 0; q < 4; ++q) \
      gload_lds16(xap[q] + (KT) * 64, (char*)smA + q * 4096 + wv * 1024); \
  } while (0)

  #define LOAD_B(KT) do { \
    _Pragma("unroll") \
    for (int q = 0; q < 8; ++q) bv1[q] = *(const float4*)(w1p + (KT) * 64 + q * 4); \
    _Pragma("unroll") \
    for (int q = 0; q < 8; ++q) bv3[q] = *(const float4*)(w3p + (KT) * 64 + q * 4); \
  } while (0)

  #define STORE_B() do { \
    _Pragma("unroll") \
    for (int q = 0; q < 4; ++q) { \
      *(bf16x8*)(smB1 + rowB * 64 + physB[q]) = pack8(bv1[2 * q], bv1[2 * q + 1]); \
      *(bf16x8*)(smB3 + rowB * 64 + physB[q]) = pack8(bv3[2 * q], bv3[2 * q + 1]); \
    } \
  } while (0)

  // prologue: tile 0 staged & published (STORE_B's counted vmcnt drains B0; FIFO covers A0 glds)
  STAGE_A(0);
  LOAD_B(0);
  STORE_B();
  __syncthreads();

  const int NKT = DDIM / 64;
  for (int kt = 0; kt < NKT; ++kt) {
    if (kt < NKT - 1) {
      LOAD_B(kt + 1);                      // reg prefetch — flies over the MFMA phase
      __builtin_amdgcn_sched_barrier(0);
    }
    #pragma unroll
    for (int kk = 0; kk < 2; ++kk) {
      const int phys = ((kk * 4 + (ln >> 4)) ^ (ln & 7)) * 8;
      bf16x8 af[4], b1f[4], b3f[4];
      #pragma unroll
      for (int mi = 0; mi < 4; ++mi)
        af[mi] = *(const bf16x8*)(smA + (wr * 64 + mi * 16 + (ln & 15)) * 64 + phys);
      #pragma unroll
      for (int ni = 0; ni < 4; ++ni) {
        b1f[ni] = *(const bf16x8*)(smB1 + (wc * 64 + ni * 16 + (ln & 15)) * 64 + phys);
        b3f[ni] = *(const bf16x8*)(smB3 + (wc * 64 + ni * 16 + (ln & 15)) * 64 + phys);
      }
      #pragma unroll
      for (int mi = 0; mi < 4; ++mi)
        #pragma unroll
        for (int ni = 0; ni < 4; ++ni) {
          accG[mi][ni] = __builtin_amdgcn_mfma_f32_16x16x32_bf16(af[mi], b1f[ni], accG[mi][ni], 0, 0, 0);
          accU[mi][ni] = __builtin_amdgcn_mfma_f32_16x16x32_bf16(af[mi], b3f[ni], accU[mi][ni], 0, 0, 0);
        }
    }
    if (kt == NKT - 1) break;
    __syncthreads();     // everyone done reading LDS; drains B[kt+1] regs (needed right now anyway)
    STORE_B();           // publish B[kt+1]
    STAGE_A(kt + 1);     // glds A[kt+1] (L2-hot, short latency)
    __syncthreads();     // publish ds_writes + drain glds
  }

  const int hbase = hoff[e];
  #pragma unroll
  for (int mi = 0; mi < 4; ++mi) {
    #pragma unroll
    for (int ni = 0; ni < 4; ++ni) {
      int col = ft * 128 + wc * 64 + ni * 16 + (ln & 15);
      #pragma unroll
      for (int r = 0; r < 4; ++r) {
        int rl = wr * 64 + mi * 16 + (ln >> 4) * 4 + r;
        int pos = mt * 128 + rl;
        if (pos < cnt) {
          float g = accG[mi][ni][r], u = accU[mi][ni][r];
          float s = g / (1.f + expf(-g));
          H[(size_t)(hbase + pos) * FDIM + col] = f2bf(s * u * smW[rl]);
        }
      }
    }
  }
  #undef STAGE_A
  #undef LOAD_B
  #undef STORE_B
}

// ---------------- GEMM2: out += H@w2^T (scatter to tokens) ----------------
__launch_bounds__(256, 3)
__global__ void gemm2_kernel(const unsigned short* __restrict__ H,
                             const float* __restrict__ w2,
                             const int* __restrict__ counts,
                             const int* __restrict__ hoff,
                             const int* __restrict__ lists,
                             float* __restrict__ out) {
  const int nt = blockIdx.x, mt = blockIdx.y, e = blockIdx.z;
  const int cnt = counts[e];
  if (mt * 128 >= cnt) return;

  __shared__ __align__(16) unsigned short smA[128 * 64];
  __shared__ __align__(16) unsigned short smB[128 * 64];
  __shared__ int smTok[128];

  const int tid = threadIdx.x;
  const int wv = tid >> 6, ln = tid & 63;
  const int wr = wv >> 1, wc = wv & 1;

  if (tid < 128) {
    int pos = mt * 128 + tid;
    smTok[tid] = (pos < cnt) ? lists[e * TTOK + pos] : -1;
  }

  const int hbase = hoff[e];
  const int colA = (((ln & 7) ^ (ln >> 3)) * 8);
  const unsigned short* hap[4];
  #pragma unroll
  for (int q = 0; q < 4; ++q)
    hap[q] = H + (size_t)(hbase + mt * 128 + q * 32 + wv * 8 + (ln >> 3)) * FDIM + colA;

  const int rowB = tid >> 1;
  const int halfB = tid & 1;
  const float* w2p = w2 + (size_t)e * DDIM * FDIM + (size_t)(nt * 128 + rowB) * FDIM + halfB * 32;
  int physB[4];
  #pragma unroll
  for (int q = 0; q < 4; ++q) physB[q] = ((halfB * 4 + q) ^ (rowB & 7)) * 8;

  float4 bv[8];

  f32x4 acc[4][4];
  #pragma unroll
  for (int i = 0; i < 4; ++i)
    #pragma unroll
    for (int j = 0; j < 4; ++j) acc[i][j] = (f32x4){0.f, 0.f, 0.f, 0.f};

  #define STAGE_A2(KT) do { \
    _Pragma("unroll") \
    for (int q = 0; q < 4; ++q) \
      gload_lds16(hap[q] + (KT) * 64, (char*)smA + q * 4096 + wv * 1024); \
  } while (0)

  #define LOAD_B2(KT) do { \
    _Pragma("unroll") \
    for (int q = 0; q < 8; ++q) bv[q] = *(const float4*)(w2p + (KT) * 64 + q * 4); \
  } while (0)

  #define STORE_B2() do { \
    _Pragma("unroll") \
    for (int q = 0; q < 4; ++q) \
      *(bf16x8*)(smB + rowB * 64 + physB[q]) = pack8(bv[2 * q], bv[2 * q + 1]); \
  } while (0)

  STAGE_A2(0);
  LOAD_B2(0);
  STORE_B2();
  __syncthreads();

  const int NKT = FDIM / 64;
  for (int kt = 0; kt < NKT; ++kt) {
    if (kt < NKT - 1) {
      LOAD_B2(kt + 1);
      __builtin_amdgcn_sched_barrier(0);
    }
    #pragma unroll
    for (int kk = 0; kk < 2; ++kk) {
      const int phys = ((kk * 4 + (ln >> 4)) ^ (ln & 7)) * 8;
      bf16x8 af[4], bf[4];
      #pragma unroll
      for (int mi = 0; mi < 4; ++mi)
        af[mi] = *(const bf16x8*)(smA + (wr * 64 + mi * 16 + (ln & 15)) * 64 + phys);
      #pragma unroll
      for (int ni = 0; ni < 4; ++ni)
        bf[ni] = *(const bf16x8*)(smB + (wc * 64 + ni * 16 + (ln & 15)) * 64 + phys);
      #pragma unroll
      for (int mi = 0; mi < 4; ++mi)
        #pragma unroll
        for (int ni = 0; ni < 4; ++ni)
          acc[mi][ni] = __builtin_amdgcn_mfma_f32_16x16x32_bf16(af[mi], bf[ni], acc[mi][ni], 0, 0, 0);
    }
    if (kt == NKT - 1) break;
    __syncthreads();
    STORE_B2();
    STAGE_A2(kt + 1);
    __syncthreads();
  }

  #pragma unroll
  for (int mi = 0; mi < 4; ++mi) {
    #pragma unroll
    for (int ni = 0; ni < 4; ++ni) {
      int col = nt * 128 + wc * 64 + ni * 16 + (ln & 15);
      #pragma unroll
      for (int r = 0; r < 4; ++r) {
        int rl = wr * 64 + mi * 16 + (ln >> 4) * 4 + r;
        int tok = smTok[rl];
        if (tok >= 0) atomicAdd(out + (size_t)tok * DDIM + col, acc[mi][ni][r]);
      }
    }
  }
  #undef STAGE_A2
  #undef LOAD_B2
  #undef STORE_B2
}

extern "C" void kernel_launch(void* const* d_in, const int* in_sizes, int n_in,
                              void* d_out, int out_size, void* d_ws, size_t ws_size,
                              hipStream_t stream) {
  const float* x  = (const float*)d_in[0];
  const float* gw = (const float*)d_in[1];
  const float* w1 = (const float*)d_in[2];
  const float* w3 = (const float*)d_in[3];
  const float* w2 = (const float*)d_in[4];
  float* out = (float*)d_out;
  char* ws = (char*)d_ws;

  unsigned short* xb = (unsigned short*)ws;
  unsigned short* H  = (unsigned short*)(ws + 8388608);
  size_t h_bytes = (size_t)(2 * TTOK + 128) * FDIM * 2;
  char* p = ws + 8388608 + h_bytes;
  int*   lists  = (int*)p;          p += NEXP * TTOK * 4;
  float* wrow   = (float*)p;        p += NEXP * TTOK * 4;
  int*   counts = (int*)p;          p += 64;
  int*   hoff   = (int*)p;

  hipMemsetAsync(d_out, 0, (size_t)TTOK * DDIM * 4, stream);
  hipMemsetAsync(counts, 0, NEXP * 4, stream);

  cvt_x_kernel<<<(TTOK * DDIM / 4 + 255) / 256, 256, 0, stream>>>(x, xb, TTOK * DDIM / 4);
  gate_kernel<<<TTOK / 4, 256, 0, stream>>>(x, gw, counts, lists, wrow);
  prefix_kernel<<<1, 64, 0, stream>>>(counts, hoff);
  gemm1_kernel<<<dim3(FDIM / 128, TTOK / 128, NEXP), 256, 0, stream>>>(
      xb, w1, w3, counts, hoff, lists, wrow, H);
  gemm2_kernel<<<dim3(DDIM / 128, TTOK / 128, NEXP), 256, 0, stream>>>(
      H, w2, counts, hoff, lists, out);
}

// Round 6
// 1082.204 us; speedup vs baseline: 3.1416x; 3.1416x over previous
//
#include <hip/hip_runtime.h>
#include <hip/hip_bf16.h>
#include <cstdint>
#include <cstddef>

#define TTOK 2048
#define DDIM 2048
#define FDIM 7168
#define NEXP 8

typedef __attribute__((ext_vector_type(8))) short bf16x8;
typedef __attribute__((ext_vector_type(4))) float f32x4;

// native RNE float->bf16 (compiler fuses pairs into v_cvt_pk_bf16_f32)
__device__ __forceinline__ unsigned short f2bf(float f) {
  __hip_bfloat16 h = __float2bfloat16(f);
  unsigned short s;
  __builtin_memcpy(&s, &h, 2);
  return s;
}

__device__ __forceinline__ bf16x8 pack8(float4 a, float4 b) {
  bf16x8 r;
  r[0] = (short)f2bf(a.x); r[1] = (short)f2bf(a.y);
  r[2] = (short)f2bf(a.z); r[3] = (short)f2bf(a.w);
  r[4] = (short)f2bf(b.x); r[5] = (short)f2bf(b.y);
  r[6] = (short)f2bf(b.z); r[7] = (short)f2bf(b.w);
  return r;
}

__device__ __forceinline__ void gload_lds16(const void* g, void* l) {
  __builtin_amdgcn_global_load_lds((const __attribute__((address_space(1))) void*)g,
                                   (__attribute__((address_space(3))) void*)l,
                                   16, 0, 0);
}

// ---------------- fp32 -> bf16 converters ----------------
__global__ void cvt_x_kernel(const float* __restrict__ x, unsigned short* __restrict__ xb, int n4) {
  int i = blockIdx.x * blockDim.x + threadIdx.x;
  if (i >= n4) return;
  float4 v = ((const float4*)x)[i];
  ushort4 o;
  o.x = f2bf(v.x); o.y = f2bf(v.y); o.z = f2bf(v.z); o.w = f2bf(v.w);
  ((ushort4*)xb)[i] = o;
}

__global__ void cvt_w_kernel(const float* __restrict__ src, unsigned short* __restrict__ dst, int n4) {
  for (int i = blockIdx.x * blockDim.x + threadIdx.x; i < n4; i += gridDim.x * blockDim.x) {
    float4 v = ((const float4*)src)[i];
    ushort4 o;
    o.x = f2bf(v.x); o.y = f2bf(v.y); o.z = f2bf(v.z); o.w = f2bf(v.w);
    ((ushort4*)dst)[i] = o;
  }
}

// ---------------- gate: fp32 logits, top-2, routing ----------------
__global__ void gate_kernel(const float* __restrict__ x, const float* __restrict__ gw,
                            int* __restrict__ counts, int* __restrict__ lists,
                            float* __restrict__ wrow) {
  const int wv = threadIdx.x >> 6, ln = threadIdx.x & 63;
  const int t = blockIdx.x * 4 + wv;
  float acc[8];
  #pragma unroll
  for (int e = 0; e < 8; ++e) acc[e] = 0.f;
  const float* xp = x + (size_t)t * DDIM;
  for (int d = ln; d < DDIM; d += 64) {
    float xv = xp[d];
    #pragma unroll
    for (int e = 0; e < 8; ++e) acc[e] += xv * gw[e * DDIM + d];
  }
  #pragma unroll
  for (int e = 0; e < 8; ++e) {
    float v = acc[e];
    #pragma unroll
    for (int off = 32; off > 0; off >>= 1) v += __shfl_down(v, off);
    acc[e] = v;
  }
  if (ln == 0) {
    int i0 = 0;
    #pragma unroll
    for (int e = 1; e < 8; ++e) if (acc[e] > acc[i0]) i0 = e;
    int i1 = (i0 == 0) ? 1 : 0;
    #pragma unroll
    for (int e = 0; e < 8; ++e) if (e != i0 && acc[e] > acc[i1]) i1 = e;
    float p1 = expf(acc[i1] - acc[i0]);
    float w0 = 1.f / (1.f + p1);
    float w1v = p1 / (1.f + p1);
    int pos0 = atomicAdd(&counts[i0], 1);
    lists[i0 * TTOK + pos0] = t; wrow[i0 * TTOK + pos0] = w0;
    int pos1 = atomicAdd(&counts[i1], 1);
    lists[i1 * TTOK + pos1] = t; wrow[i1 * TTOK + pos1] = w1v;
  }
}

__global__ void prefix_kernel(const int* __restrict__ counts, int* __restrict__ hoff) {
  if (threadIdx.x == 0) {
    int s = 0;
    for (int e = 0; e < NEXP; ++e) { hoff[e] = s; s += counts[e]; }
  }
}

// LDS tile: logical [128 rows][8 chunks of 8 bf16]; physical chunk = logical ^ (row&7).
// glds writes linearly; source column is pre-swizzled: colSwz = ((ln&7)^(ln>>3))*8.

// ======== bf16-weight path (m97 structure: glds both operands, single-buffered) ========

__launch_bounds__(256, 2)
__global__ void gemm1b_kernel(const unsigned short* __restrict__ xb,
                              const unsigned short* __restrict__ w1b,
                              const unsigned short* __restrict__ w3b,
                              const int* __restrict__ counts,
                              const int* __restrict__ hoff,
                              const int* __restrict__ lists,
                              const float* __restrict__ wrow,
                              unsigned short* __restrict__ H) {
  const int ft = blockIdx.x, mt = blockIdx.y, e = blockIdx.z;
  const int cnt = counts[e];
  if (mt * 128 >= cnt) return;

  __shared__ __align__(16) unsigned short smA[128 * 64];
  __shared__ __align__(16) unsigned short smB1[128 * 64];
  __shared__ __align__(16) unsigned short smB3[128 * 64];
  __shared__ float smW[128];

  const int tid = threadIdx.x;
  const int wv = tid >> 6, ln = tid & 63;
  const int wr = wv >> 1, wc = wv & 1;

  if (tid < 128) {
    int pos = mt * 128 + tid;
    smW[tid] = (pos < cnt) ? wrow[e * TTOK + pos] : 0.f;
  }

  const int colSwz = (((ln & 7) ^ (ln >> 3)) * 8);
  const int rlocal = wv * 8 + (ln >> 3);   // row within each 32-row q-group

  // A (gathered token rows)
  const int* lst = lists + e * TTOK;
  const unsigned short* xap[4];
  #pragma unroll
  for (int q = 0; q < 4; ++q) {
    int pos = mt * 128 + q * 32 + rlocal;
    int tok = (pos < cnt) ? lst[pos] : 0;
    xap[q] = xb + (size_t)tok * DDIM + colSwz;
  }
  // B1/B3 (bf16 weights, row-major [F][D] per expert)
  const size_t eoff = (size_t)e * FDIM * DDIM;
  const unsigned short* b1p[4];
  const unsigned short* b3p[4];
  #pragma unroll
  for (int q = 0; q < 4; ++q) {
    size_t row = (size_t)(ft * 128 + q * 32 + rlocal);
    b1p[q] = w1b + eoff + row * DDIM + colSwz;
    b3p[q] = w3b + eoff + row * DDIM + colSwz;
  }

  f32x4 accG[4][4], accU[4][4];
  #pragma unroll
  for (int i = 0; i < 4; ++i)
    #pragma unroll
    for (int j = 0; j < 4; ++j) {
      accG[i][j] = (f32x4){0.f, 0.f, 0.f, 0.f};
      accU[i][j] = (f32x4){0.f, 0.f, 0.f, 0.f};
    }

  const int NKT = DDIM / 64;
  for (int kt = 0; kt < NKT; ++kt) {
    #pragma unroll
    for (int q = 0; q < 4; ++q) {
      gload_lds16(xap[q] + kt * 64, (char*)smA  + q * 4096 + wv * 1024);
      gload_lds16(b1p[q] + kt * 64, (char*)smB1 + q * 4096 + wv * 1024);
      gload_lds16(b3p[q] + kt * 64, (char*)smB3 + q * 4096 + wv * 1024);
    }
    __syncthreads();   // drains glds (vmcnt 0)

    #pragma unroll
    for (int kk = 0; kk < 2; ++kk) {
      const int phys = ((kk * 4 + (ln >> 4)) ^ (ln & 7)) * 8;
      bf16x8 af[4], b1f[4], b3f[4];
      #pragma unroll
      for (int mi = 0; mi < 4; ++mi)
        af[mi] = *(const bf16x8*)(smA + (wr * 64 + mi * 16 + (ln & 15)) * 64 + phys);
      #pragma unroll
      for (int ni = 0; ni < 4; ++ni) {
        b1f[ni] = *(const bf16x8*)(smB1 + (wc * 64 + ni * 16 + (ln & 15)) * 64 + phys);
        b3f[ni] = *(const bf16x8*)(smB3 + (wc * 64 + ni * 16 + (ln & 15)) * 64 + phys);
      }
      #pragma unroll
      for (int mi = 0; mi < 4; ++mi)
        #pragma unroll
        for (int ni = 0; ni < 4; ++ni) {
          accG[mi][ni] = __builtin_amdgcn_mfma_f32_16x16x32_bf16(af[mi], b1f[ni], accG[mi][ni], 0, 0, 0);
          accU[mi][ni] = __builtin_amdgcn_mfma_f32_16x16x32_bf16(af[mi], b3f[ni], accU[mi][ni], 0, 0, 0);
        }
    }
    __syncthreads();   // LDS reads done before next-step overwrite
  }

  const int hbase = hoff[e];
  #pragma unroll
  for (int mi = 0; mi < 4; ++mi) {
    #pragma unroll
    for (int ni = 0; ni < 4; ++ni) {
      int col = ft * 128 + wc * 64 + ni * 16 + (ln & 15);
      #pragma unroll
      for (int r = 0; r < 4; ++r) {
        int rl = wr * 64 + mi * 16 + (ln >> 4) * 4 + r;
        int pos = mt * 128 + rl;
        if (pos < cnt) {
          float g = accG[mi][ni][r], u = accU[mi][ni][r];
          float s = g / (1.f + expf(-g));
          H[(size_t)(hbase + pos) * FDIM + col] = f2bf(s * u * smW[rl]);
        }
      }
    }
  }
}

__launch_bounds__(256, 2)
__global__ void gemm2b_kernel(const unsigned short* __restrict__ H,
                              const unsigned short* __restrict__ w2b,
                              const int* __restrict__ counts,
                              const int* __restrict__ hoff,
                              const int* __restrict__ lists,
                              float* __restrict__ out) {
  const int nt = blockIdx.x, mt = blockIdx.y, e = blockIdx.z;
  const int cnt = counts[e];
  if (mt * 128 >= cnt) return;

  __shared__ __align__(16) unsigned short smA[128 * 64];
  __shared__ __align__(16) unsigned short smB[128 * 64];
  __shared__ int smTok[128];

  const int tid = threadIdx.x;
  const int wv = tid >> 6, ln = tid & 63;
  const int wr = wv >> 1, wc = wv & 1;

  if (tid < 128) {
    int pos = mt * 128 + tid;
    smTok[tid] = (pos < cnt) ? lists[e * TTOK + pos] : -1;
  }

  const int colSwz = (((ln & 7) ^ (ln >> 3)) * 8);
  const int rlocal = wv * 8 + (ln >> 3);
  const int hbase = hoff[e];

  const unsigned short* hap[4];
  const unsigned short* b2p[4];
  #pragma unroll
  for (int q = 0; q < 4; ++q) {
    hap[q] = H + (size_t)(hbase + mt * 128 + q * 32 + rlocal) * FDIM + colSwz;
    b2p[q] = w2b + (size_t)e * DDIM * FDIM + (size_t)(nt * 128 + q * 32 + rlocal) * FDIM + colSwz;
  }

  f32x4 acc[4][4];
  #pragma unroll
  for (int i = 0; i < 4; ++i)
    #pragma unroll
    for (int j = 0; j < 4; ++j) acc[i][j] = (f32x4){0.f, 0.f, 0.f, 0.f};

  const int NKT = FDIM / 64;
  for (int kt = 0; kt < NKT; ++kt) {
    #pragma unroll
    for (int q = 0; q < 4; ++q) {
      gload_lds16(hap[q] + kt * 64, (char*)smA + q * 4096 + wv * 1024);
      gload_lds16(b2p[q] + kt * 64, (char*)smB + q * 4096 + wv * 1024);
    }
    __syncthreads();

    #pragma unroll
    for (int kk = 0; kk < 2; ++kk) {
      const int phys = ((kk * 4 + (ln >> 4)) ^ (ln & 7)) * 8;
      bf16x8 af[4], bf[4];
      #pragma unroll
      for (int mi = 0; mi < 4; ++mi)
        af[mi] = *(const bf16x8*)(smA + (wr * 64 + mi * 16 + (ln & 15)) * 64 + phys);
      #pragma unroll
      for (int ni = 0; ni < 4; ++ni)
        bf[ni] = *(const bf16x8*)(smB + (wc * 64 + ni * 16 + (ln & 15)) * 64 + phys);
      #pragma unroll
      for (int mi = 0; mi < 4; ++mi)
        #pragma unroll
        for (int ni = 0; ni < 4; ++ni)
          acc[mi][ni] = __builtin_amdgcn_mfma_f32_16x16x32_bf16(af[mi], bf[ni], acc[mi][ni], 0, 0, 0);
    }
    __syncthreads();
  }

  #pragma unroll
  for (int mi = 0; mi < 4; ++mi) {
    #pragma unroll
    for (int ni = 0; ni < 4; ++ni) {
      int col = nt * 128 + wc * 64 + ni * 16 + (ln & 15);
      #pragma unroll
      for (int r = 0; r < 4; ++r) {
        int rl = wr * 64 + mi * 16 + (ln >> 4) * 4 + r;
        int tok = smTok[rl];
        if (tok >= 0) atomicAdd(out + (size_t)tok * DDIM + col, acc[mi][ni][r]);
      }
    }
  }
}

// ======== fallback path (round-4, fp32 reg-staged B) — used only if ws too small ========

__launch_bounds__(256, 2)
__global__ void gemm1_kernel(const unsigned short* __restrict__ xb,
                             const float* __restrict__ w1,
                             const float* __restrict__ w3,
                             const int* __restrict__ counts,
                             const int* __restrict__ hoff,
                             const int* __restrict__ lists,
                             const float* __restrict__ wrow,
                             unsigned short* __restrict__ H) {
  const int ft = blockIdx.x, mt = blockIdx.y, e = blockIdx.z;
  const int cnt = counts[e];
  if (mt * 128 >= cnt) return;

  __shared__ __align__(16) unsigned short smA[128 * 64];
  __shared__ __align__(16) unsigned short smB1[128 * 64];
  __shared__ __align__(16) unsigned short smB3[128 * 64];
  __shared__ float smW[128];

  const int tid = threadIdx.x;
  const int wv = tid >> 6, ln = tid & 63;
  const int wr = wv >> 1, wc = wv & 1;

  if (tid < 128) {
    int pos = mt * 128 + tid;
    smW[tid] = (pos < cnt) ? wrow[e * TTOK + pos] : 0.f;
  }

  const int* lst = lists + e * TTOK;
  const int colA = (((ln & 7) ^ (ln >> 3)) * 8);
  const unsigned short* xap[4];
  #pragma unroll
  for (int q = 0; q < 4; ++q) {
    int pos = mt * 128 + q * 32 + wv * 8 + (ln >> 3);
    int tok = (pos < cnt) ? lst[pos] : 0;
    xap[q] = xb + (size_t)tok * DDIM + colA;
  }

  const int rowB = tid >> 1;
  const int halfB = tid & 1;
  const size_t eoff = (size_t)e * FDIM * DDIM;
  const float* w1p = w1 + eoff + (size_t)(ft * 128 + rowB) * DDIM + halfB * 32;
  const float* w3p = w3 + eoff + (size_t)(ft * 128 + rowB) * DDIM + halfB * 32;
  int physB[4];
  #pragma unroll
  for (int q = 0; q < 4; ++q) physB[q] = ((halfB * 4 + q) ^ (rowB & 7)) * 8;

  float4 bv1[8], bv3[8];
  f32x4 accG[4][4], accU[4][4];
  #pragma unroll
  for (int i = 0; i < 4; ++i)
    #pragma unroll
    for (int j = 0; j < 4; ++j) {
      accG[i][j] = (f32x4){0.f, 0.f, 0.f, 0.f};
      accU[i][j] = (f32x4){0.f, 0.f, 0.f, 0.f};
    }

  #define STAGE_A(KT) do { \
    _Pragma("unroll") \
    for (int q = 0; q < 4; ++q) \
      gload_lds16(xap[q] + (KT) * 64, (char*)smA + q * 4096 + wv * 1024); \
  } while (0)
  #define LOAD_B(KT) do { \
    _Pragma("unroll") \
    for (int q = 0; q < 8; ++q) bv1[q] = *(const float4*)(w1p + (KT) * 64 + q * 4); \
    _Pragma("unroll") \
    for (int q = 0; q < 8; ++q) bv3[q] = *(const float4*)(w3p + (KT) * 64 + q * 4); \
  } while (0)
  #define STORE_B() do { \
    _Pragma("unroll") \
    for (int q = 0; q < 4; ++q) { \
      *(bf16x8*)(smB1 + rowB * 64 + physB[q]) = pack8(bv1[2 * q], bv1[2 * q + 1]); \
      *(bf16x8*)(smB3 + rowB * 64 + physB[q]) = pack8(bv3[2 * q], bv3[2 * q + 1]); \
    } \
  } while (0)

  STAGE_A(0);
  LOAD_B(0);
  STORE_B();
  __syncthreads();

  const int NKT = DDIM / 64;
  for (int kt = 0; kt < NKT; ++kt) {
    if (kt < NKT - 1) {
      LOAD_B(kt + 1);
      __builtin_amdgcn_sched_barrier(0);
    }
    #pragma unroll
    for (int kk = 0; kk < 2; ++kk) {
      const int phys = ((kk * 4 + (ln >> 4)) ^ (ln & 7)) * 8;
      bf16x8 af[4], b1f[4], b3f[4];
      #pragma unroll
      for (int mi = 0; mi < 4; ++mi)
        af[mi] = *(const bf16x8*)(smA + (wr * 64 + mi * 16 + (ln & 15)) * 64 + phys);
      #pragma unroll
      for (int ni = 0; ni < 4; ++ni) {
        b1f[ni] = *(const bf16x8*)(smB1 + (wc * 64 + ni * 16 + (ln & 15)) * 64 + phys);
        b3f[ni] = *(const bf16x8*)(smB3 + (wc * 64 + ni * 16 + (ln & 15)) * 64 + phys);
      }
      #pragma unroll
      for (int mi = 0; mi < 4; ++mi)
        #pragma unroll
        for (int ni = 0; ni < 4; ++ni) {
          accG[mi][ni] = __builtin_amdgcn_mfma_f32_16x16x32_bf16(af[mi], b1f[ni], accG[mi][ni], 0, 0, 0);
          accU[mi][ni] = __builtin_amdgcn_mfma_f32_16x16x32_bf16(af[mi], b3f[ni], accU[mi][ni], 0, 0, 0);
        }
    }
    if (kt == NKT - 1) break;
    __syncthreads();
    STORE_B();
    STAGE_A(kt + 1);
    __syncthreads();
  }

  const int hbase = hoff[e];
  #pragma unroll
  for (int mi = 0; mi < 4; ++mi) {
    #pragma unroll
    for (int ni = 0; ni < 4; ++ni) {
      int col = ft * 128 + wc * 64 + ni * 16 + (ln & 15);
      #pragma unroll
      for (int r = 0; r < 4; ++r) {
        int rl = wr * 64 + mi * 16 + (ln >> 4) * 4 + r;
        int pos = mt * 128 + rl;
        if (pos < cnt) {
          float g = accG[mi][ni][r], u = accU[mi][ni][r];
          float s = g / (1.f + expf(-g));
          H[(size_t)(hbase + pos) * FDIM + col] = f2bf(s * u * smW[rl]);
        }
      }
    }
  }
  #undef STAGE_A
  #undef LOAD_B
  #undef STORE_B
}

__launch_bounds__(256, 2)
__global__ void gemm2_kernel(const unsigned short* __restrict__ H,
                             const float* __restrict__ w2,
                             const int* __restrict__ counts,
                             const int* __restrict__ hoff,
                             const int* __restrict__ lists,
                             float* __restrict__ out) {
  const int nt = blockIdx.x, mt = blockIdx.y, e = blockIdx.z;
  const int cnt = counts[e];
  if (mt * 128 >= cnt) return;

  __shared__ __align__(16) unsigned short smA[128 * 64];
  __shared__ __align__(16) unsigned short smB[128 * 64];
  __shared__ int smTok[128];

  const int tid = threadIdx.x;
  const int wv = tid >> 6, ln = tid & 63;
  const int wr = wv >> 1, wc = wv & 1;

  if (tid < 128) {
    int pos = mt * 128 + tid;
    smTok[tid] = (pos < cnt) ? lists[e * TTOK + pos] : -1;
  }

  const int hbase = hoff[e];
  const int colA = (((ln & 7) ^ (ln >> 3)) * 8);
  const unsigned short* hap[4];
  #pragma unroll
  for (int q = 0; q < 4; ++q)
    hap[q] = H + (size_t)(hbase + mt * 128 + q * 32 + wv * 8 + (ln >> 3)) * FDIM + colA;

  const int rowB = tid >> 1;
  const int halfB = tid & 1;
  const float* w2p = w2 + (size_t)e * DDIM * FDIM + (size_t)(nt * 128 + rowB) * FDIM + halfB * 32;
  int physB[4];
  #pragma unroll
  for (int q = 0; q < 4; ++q) physB[q] = ((halfB * 4 + q) ^ (rowB & 7)) * 8;

  float4 bv[8];
  f32x4 acc[4][4];
  #pragma unroll
  for (int i = 0; i < 4; ++i)
    #pragma unroll
    for (int j = 0; j < 4; ++j) acc[i][j] = (f32x4){0.f, 0.f, 0.f, 0.f};

  #define STAGE_A2(KT) do { \
    _Pragma("unroll") \
    for (int q = 0; q < 4; ++q) \
      gload_lds16(hap[q] + (KT) * 64, (char*)smA + q * 4096 + wv * 1024); \
  } while (0)
  #define LOAD_B2(KT) do { \
    _Pragma("unroll") \
    for (int q = 0; q < 8; ++q) bv[q] = *(const float4*)(w2p + (KT) * 64 + q * 4); \
  } while (0)
  #define STORE_B2() do { \
    _Pragma("unroll") \
    for (int q = 0; q < 4; ++q) \
      *(bf16x8*)(smB + rowB * 64 + physB[q]) = pack8(bv[2 * q], bv[2 * q + 1]); \
  } while (0)

  STAGE_A2(0);
  LOAD_B2(0);
  STORE_B2();
  __syncthreads();

  const int NKT = FDIM / 64;
  for (int kt = 0; kt < NKT; ++kt) {
    if (kt < NKT - 1) {
      LOAD_B2(kt + 1);
      __builtin_amdgcn_sched_barrier(0);
    }
    #pragma unroll
    for (int kk = 0; kk < 2; ++kk) {
      const int phys = ((kk * 4 + (ln >> 4)) ^ (ln & 7)) * 8;
      bf16x8 af[4], bf[4];
      #pragma unroll
      for (int mi = 0; mi < 4; ++mi)
        af[mi] = *(const bf16x8*)(smA + (wr * 64 + mi * 16 + (ln & 15)) * 64 + phys);
      #pragma unroll
      for (int ni = 0; ni < 4; ++ni)
        bf[ni] = *(const bf16x8*)(smB + (wc * 64 + ni * 16 + (ln & 15)) * 64 + phys);
      #pragma unroll
      for (int mi = 0; mi < 4; ++mi)
        #pragma unroll
        for (int ni = 0; ni < 4; ++ni)
          acc[mi][ni] = __builtin_amdgcn_mfma_f32_16x16x32_bf16(af[mi], bf[ni], acc[mi][ni], 0, 0, 0);
    }
    if (kt == NKT - 1) break;
    __syncthreads();
    STORE_B2();
    STAGE_A2(kt + 1);
    __syncthreads();
  }

  #pragma unroll
  for (int mi = 0; mi < 4; ++mi) {
    #pragma unroll
    for (int ni = 0; ni < 4; ++ni) {
      int col = nt * 128 + wc * 64 + ni * 16 + (ln & 15);
      #pragma unroll
      for (int r = 0; r < 4; ++r) {
        int rl = wr * 64 + mi * 16 + (ln >> 4) * 4 + r;
        int tok = smTok[rl];
        if (tok >= 0) atomicAdd(out + (size_t)tok * DDIM + col, acc[mi][ni][r]);
      }
    }
  }
  #undef STAGE_A2
  #undef LOAD_B2
  #undef STORE_B2
}

extern "C" void kernel_launch(void* const* d_in, const int* in_sizes, int n_in,
                              void* d_out, int out_size, void* d_ws, size_t ws_size,
                              hipStream_t stream) {
  const float* x  = (const float*)d_in[0];
  const float* gw = (const float*)d_in[1];
  const float* w1 = (const float*)d_in[2];
  const float* w3 = (const float*)d_in[3];
  const float* w2 = (const float*)d_in[4];
  float* out = (float*)d_out;
  char* ws = (char*)d_ws;

  const size_t XB_BYTES = (size_t)TTOK * DDIM * 2;                 // 8,388,608
  const size_t H_BYTES  = (size_t)(2 * TTOK + 128) * FDIM * 2;     // 60,555,264
  const size_t W_ELEMS  = (size_t)NEXP * FDIM * DDIM;              // 117,440,512
  const size_t WB_BYTES = W_ELEMS * 2;                             // 234,881,024
  const size_t META_BYTES = (size_t)NEXP * TTOK * 4 * 2 + 128;

  unsigned short* xb = (unsigned short*)ws;
  unsigned short* H  = (unsigned short*)(ws + XB_BYTES);

  const size_t need_bf16 = XB_BYTES + H_BYTES + 3 * WB_BYTES + META_BYTES;
  const bool use_bf16w = (ws_size >= need_bf16);

  char* p;
  unsigned short *w1b = nullptr, *w3b = nullptr, *w2b = nullptr;
  if (use_bf16w) {
    w1b = (unsigned short*)(ws + XB_BYTES + H_BYTES);
    w3b = (unsigned short*)((char*)w1b + WB_BYTES);
    w2b = (unsigned short*)((char*)w3b + WB_BYTES);
    p = (char*)w2b + WB_BYTES;
  } else {
    p = ws + XB_BYTES + H_BYTES;
  }
  int*   lists  = (int*)p;          p += NEXP * TTOK * 4;
  float* wrow   = (float*)p;        p += NEXP * TTOK * 4;
  int*   counts = (int*)p;          p += 64;
  int*   hoff   = (int*)p;

  hipMemsetAsync(d_out, 0, (size_t)TTOK * DDIM * 4, stream);
  hipMemsetAsync(counts, 0, NEXP * 4, stream);

  cvt_x_kernel<<<(TTOK * DDIM / 4 + 255) / 256, 256, 0, stream>>>(x, xb, TTOK * DDIM / 4);
  gate_kernel<<<TTOK / 4, 256, 0, stream>>>(x, gw, counts, lists, wrow);
  prefix_kernel<<<1, 64, 0, stream>>>(counts, hoff);

  if (use_bf16w) {
    const int n4 = (int)(W_ELEMS / 4);   // 29,360,128
    cvt_w_kernel<<<4096, 256, 0, stream>>>(w1, w1b, n4);
    cvt_w_kernel<<<4096, 256, 0, stream>>>(w3, w3b, n4);
    cvt_w_kernel<<<4096, 256, 0, stream>>>(w2, w2b, n4);
    gemm1b_kernel<<<dim3(FDIM / 128, TTOK / 128, NEXP), 256, 0, stream>>>(
        xb, w1b, w3b, counts, hoff, lists, wrow, H);
    gemm2b_kernel<<<dim3(DDIM / 128, TTOK / 128, NEXP), 256, 0, stream>>>(
        H, w2b, counts, hoff, lists, out);
  } else {
    gemm1_kernel<<<dim3(FDIM / 128, TTOK / 128, NEXP), 256, 0, stream>>>(
        xb, w1, w3, counts, hoff, lists, wrow, H);
    gemm2_kernel<<<dim3(DDIM / 128, TTOK / 128, NEXP), 256, 0, stream>>>(
        H, w2, counts, hoff, lists, out);
  }
}